// Round 15
// baseline (470.278 us; speedup 1.0000x reference)
//
#include <hip/hip_runtime.h>

// ---------------------------------------------------------------------------
// LoRA QKV fused projection on MI355X (gfx950)
// Weff-folding (LoRA into weights) + ONE bf16 MFMA GEMM + NT epilogue stores.
// R15: occupancy retry with a register-feasible geometry.
//   BM x BN = 256 x 128, 8 waves (4M x 2N), per-wave 64x64 -> acc = 64 VGPRs
//   (R10's 128-acc made 2 blocks/CU impossible; this doesn't). LDS = 2-slot
//   ring of 24KB slices = 48KB -> 2 blocks/CU fit both LDS (96<=160KB) and
//   registers (est. ~120 <= 128). One phase per K-slice (8 ds_read + 16 MFMA,
//   R4 grain), 2 barriers/slice (was 4). Cross-block overlap fills the
//   barrier gap (m114 mechanism) — the ~40% of slice time neither pipe uses.
//   launch_bounds (512,2): cap 256, NO spill risk; occupancy via actual alloc.
// ---------------------------------------------------------------------------

#define GLOBAL_AS __attribute__((address_space(1)))
#define LDS_AS    __attribute__((address_space(3)))

typedef __attribute__((ext_vector_type(8))) short  short8;   // 8 bf16 (MFMA A/B frag)
typedef __attribute__((ext_vector_type(4))) float  floatx4;  // MFMA C/D frag

constexpr int Mdim = 8192;   // B*S
constexpr int Kdim = 4096;   // H
constexpr int NQ   = 4096;
constexpr int NKV  = 1024;
constexpr int NTOT = NQ + 2 * NKV;  // 6144
constexpr float LORA_SCALE = 2.0f;

constexpr int BM = 256, BN = 128;
constexpr int TILES_M = Mdim / BM;      // 32
constexpr int TILES_N = NTOT / BN;      // 48
constexpr int NWG = TILES_M * TILES_N;  // 1536 (%8==0 -> bijective XCD swizzle)
constexpr int NSLICE = Kdim / 32;       // 128 K-slices of 32

constexpr int WEFF_BLOCKS = (NTOT / 64) * (Kdim / 512);  // 768
constexpr int CVT_BLOCKS  = 2048;
constexpr int AT_STRIDE   = 516;

__device__ __forceinline__ unsigned short f2bf(float f) {
    union { float f; unsigned int u; } a; a.f = f;
    unsigned int r = a.u + 0x7FFFu + ((a.u >> 16) & 1u);
    return (unsigned short)(r >> 16);
}

// ---------------------------------------------------------------------------
// Fused prep (unchanged):
//   blocks [0, WEFF_BLOCKS): Weff[n,h] = W[n,h] + 2*sum_r A[h,r]B[r,n] -> bf16
//   blocks [WEFF_BLOCKS, +CVT_BLOCKS): X fp32 -> bf16.
// ---------------------------------------------------------------------------
__global__ __launch_bounds__(256)
void prep_kernel(const float4* __restrict__ x4, unsigned short* __restrict__ Xbf,
                 const float* __restrict__ Wq, const float* __restrict__ Wk,
                 const float* __restrict__ Wv,
                 const float* __restrict__ Aq, const float* __restrict__ Bq,
                 const float* __restrict__ Ak, const float* __restrict__ Bk,
                 const float* __restrict__ Av, const float* __restrict__ Bv,
                 unsigned short* __restrict__ Wf) {
    __shared__ float AsT[16 * AT_STRIDE];   // ~33 KB: A^T chunk, [r][h_local]
    __shared__ float Bsc[64 * 16];          // 4 KB: 2*B[r, n0+..] as [n][r]

    const int tid = threadIdx.x;

    if (blockIdx.x >= WEFF_BLOCKS) {
        int i = (blockIdx.x - WEFF_BLOCKS) * 256 + tid;
        const int stride = CVT_BLOCKS * 256;
        const int n4 = Mdim * Kdim / 4;
        ushort4* out = (ushort4*)Xbf;
        for (; i < n4; i += stride) {
            float4 v = x4[i];
            ushort4 u;
            u.x = f2bf(v.x); u.y = f2bf(v.y); u.z = f2bf(v.z); u.w = f2bf(v.w);
            out[i] = u;
        }
        return;
    }

    const int n0 = (blockIdx.x >> 3) * 64;      // 64-row group (never straddles seg)
    const int h0 = (blockIdx.x & 7) * 512;

    const float* W; const float* A; const float* Bm; int O; int nn0;
    if (n0 < NQ)            { W = Wq; A = Aq; Bm = Bq; O = NQ;  nn0 = n0; }
    else if (n0 < NQ + NKV) { W = Wk; A = Ak; Bm = Bk; O = NKV; nn0 = n0 - NQ; }
    else                    { W = Wv; A = Av; Bm = Bv; O = NKV; nn0 = n0 - NQ - NKV; }

    {
        const float4* Af4 = (const float4*)(A) + h0 * 4;
        #pragma unroll
        for (int i = 0; i < 8; ++i) {
            const int f = i * 256 + tid;
            const float4 v = Af4[f];
            const int hl = f >> 2;
            const int r0 = (f & 3) * 4;
            AsT[(r0 + 0) * AT_STRIDE + hl] = v.x;
            AsT[(r0 + 1) * AT_STRIDE + hl] = v.y;
            AsT[(r0 + 2) * AT_STRIDE + hl] = v.z;
            AsT[(r0 + 3) * AT_STRIDE + hl] = v.w;
        }
    }
    {
        const int nl = tid & 63;
        const int rq = tid >> 6;        // 0..3
        #pragma unroll
        for (int j = 0; j < 4; ++j) {
            const int r = rq * 4 + j;
            Bsc[nl * 16 + r] = Bm[r * O + nn0 + nl] * LORA_SCALE;
        }
    }
    __syncthreads();

    const int wv_ = tid >> 6;
    const int lane = tid & 63;

    #pragma unroll
    for (int pass = 0; pass < 2; ++pass) {
        const int hl = pass * 256 + lane * 4;
        float4 areg[16];
        #pragma unroll
        for (int r = 0; r < 16; ++r)
            areg[r] = *(const float4*)(&AsT[r * AT_STRIDE + hl]);

        for (int i = 0; i < 16; ++i) {
            const int nl = wv_ * 16 + i;
            const float4 w4 = *(const float4*)(W + (size_t)(nn0 + nl) * Kdim + h0 + hl);
            const float4* b4 = (const float4*)(&Bsc[nl * 16]);
            float4 d = {0.f, 0.f, 0.f, 0.f};
            #pragma unroll
            for (int q = 0; q < 4; ++q) {
                const float4 b = b4[q];
                d.x += areg[q*4+0].x * b.x + areg[q*4+1].x * b.y + areg[q*4+2].x * b.z + areg[q*4+3].x * b.w;
                d.y += areg[q*4+0].y * b.x + areg[q*4+1].y * b.y + areg[q*4+2].y * b.z + areg[q*4+3].y * b.w;
                d.z += areg[q*4+0].z * b.x + areg[q*4+1].z * b.y + areg[q*4+2].z * b.z + areg[q*4+3].z * b.w;
                d.w += areg[q*4+0].w * b.x + areg[q*4+1].w * b.y + areg[q*4+2].w * b.z + areg[q*4+3].w * b.w;
            }
            ushort4 u;
            u.x = f2bf(w4.x + d.x); u.y = f2bf(w4.y + d.y);
            u.z = f2bf(w4.z + d.z); u.w = f2bf(w4.w + d.w);
            *(ushort4*)(Wf + (size_t)(n0 + nl) * Kdim + h0 + hl) = u;
        }
    }
}

// ---------------------------------------------------------------------------
// GEMM: out[M, NTOT] = Xbf[M,K] . Wf[NTOT,K]^T + bias, scattered to q/k/v.
//
// LDS: 2-slot ring; A-slice = 16KB ([half][128 rows][64B], R4 swizzle),
// B-slice = 8KB ([128 rows][64B]). Total 48KB -> 2 blocks/CU.
// Wave (wm,wn) = (w>>1, w&1) owns a 64x64 output tile: acc[4][4] = 64 regs.
//
// Per K-slice s (slot = s&1), ONE phase:
//   ds_read 4 A-frags + 4 B-frags (b128, conflict-free swizzle);
//   lgkmcnt(0); s_barrier            <- all waves' reads of slot s done
//   STAGE slice s+2 -> slot (3 gloads: 2xA, 1xB; just-freed slot)
//   setprio(1); 16 MFMA; setprio(0);
//   vmcnt(3); s_barrier              <- slice s+1 (staged last phase) landed
// vmcnt ledger (3 loads/slice): steady outstanding {s+1:3, s+2:3}=6 ->
// vmcnt(3) retires s+1. Prologue stages 0,1; vmcnt(3) lands 0. Tail: end of
// 125 lands 126; s=126 no stage, vmcnt(0) lands 127; s=127 bare.
// Epilogue: bias + scatter, NONTEMPORAL stores (R11's verified win).
// ---------------------------------------------------------------------------
__global__ __launch_bounds__(512, 2)
void gemm_qkv_kernel(const unsigned short* __restrict__ X,
                     const unsigned short* __restrict__ Wf,
                     const float* __restrict__ bq, const float* __restrict__ bk,
                     const float* __restrict__ bv,
                     float* __restrict__ out) {
    __shared__ __align__(16) unsigned short Abuf[2][8192];  // 32 KB (2 x 16KB)
    __shared__ __align__(16) unsigned short Bbuf[2][4096];  // 16 KB (2 x 8KB)

    const int tid  = threadIdx.x;
    const int lane = tid & 63;
    const int w    = tid >> 6;
    const int wm   = w >> 1;        // 0..3  (M quarter, 64 rows)
    const int wn   = w & 1;         // 0..1  (N half, 64 cols)

    int bid = blockIdx.x;
    bid = (bid & 7) * (NWG / 8) + (bid >> 3);   // XCD-aware, bijective (1536%8==0)
    const int row0 = (bid / TILES_N) * BM;
    const int col0 = (bid % TILES_N) * BN;

    // ds_read addressing (R4's 16-B-chunk swizzle, conflict-free):
    // row bits 1-2 come from lane&15 only (wm*64/wn*64/mf*16 don't touch them)
    const int swz    = (((lane >> 4) ^ ((lane >> 1) & 3)) << 4);    // bytes
    const int aByte0 = (wm >> 1) * 8192 + ((wm & 1) * 64 + (lane & 15)) * 64 + swz;
    const int bByte0 = (wn * 64 + (lane & 15)) * 64 + swz;

    // staging source addressing (pre-permuted k -> linear LDS dest = swizzled)
    const int srow = (w << 4) + (lane >> 2);                         // 0..127
    const int kswz = (((lane & 3) ^ ((lane >> 3) & 3)) << 3);        // elements
    const unsigned short* pA0 = X  + (size_t)(row0 + srow) * Kdim + kswz;
    const unsigned short* pA1 = pA0 + (size_t)128 * Kdim;
    const unsigned short* pB  = Wf + (size_t)(col0 + srow) * Kdim + kswz;

    floatx4 acc[4][4];
    #pragma unroll
    for (int i = 0; i < 4; ++i)
        #pragma unroll
        for (int j = 0; j < 4; ++j)
            acc[i][j] = (floatx4){0.f, 0.f, 0.f, 0.f};

// 3 gloads per slice: A rows 0-127, A rows 128-255, B rows 0-127
#define STAGE3(SS, SLOT)                                                         \
    { const int ss_ = (SS);                                                      \
      __builtin_amdgcn_global_load_lds((const GLOBAL_AS void*)(pA0 + ss_ * 32),  \
          (LDS_AS void*)(&Abuf[SLOT][w * 512]),        16, 0, 0);                \
      __builtin_amdgcn_global_load_lds((const GLOBAL_AS void*)(pA1 + ss_ * 32),  \
          (LDS_AS void*)(&Abuf[SLOT][4096 + w * 512]), 16, 0, 0);                \
      __builtin_amdgcn_global_load_lds((const GLOBAL_AS void*)(pB + ss_ * 32),   \
          (LDS_AS void*)(&Bbuf[SLOT][w * 512]),        16, 0, 0); }

// WM: 0 none, 1 vmcnt(3), 2 vmcnt(0)
#define SLICE_PHASE(SLOT, DOSTAGE, SS, WM)                                       \
    { const char* ab_ = (const char*)Abuf + (SLOT) * 16384;                      \
      const char* bb_ = (const char*)Bbuf + (SLOT) * 8192;                       \
      short8 af[4], bfr[4];                                                      \
      _Pragma("unroll")                                                          \
      for (int mf = 0; mf < 4; ++mf)                                             \
        af[mf] = *(const short8*)(ab_ + aByte0 + mf * 1024);                     \
      _Pragma("unroll")                                                          \
      for (int nf = 0; nf < 4; ++nf)                                             \
        bfr[nf] = *(const short8*)(bb_ + bByte0 + nf * 1024);                    \
      asm volatile("s_waitcnt lgkmcnt(0)" ::: "memory");                         \
      __builtin_amdgcn_s_barrier();        /* all reads of this slot done */     \
      if (DOSTAGE) STAGE3(SS, SLOT);       /* overwrite freed slot */            \
      __builtin_amdgcn_s_setprio(1);                                             \
      _Pragma("unroll")                                                          \
      for (int mf = 0; mf < 4; ++mf)                                             \
        _Pragma("unroll")                                                        \
        for (int nf = 0; nf < 4; ++nf)                                           \
          acc[mf][nf] = __builtin_amdgcn_mfma_f32_16x16x32_bf16(                 \
              af[mf], bfr[nf], acc[mf][nf], 0, 0, 0);                            \
      __builtin_amdgcn_s_setprio(0);                                             \
      if ((WM) == 1) asm volatile("s_waitcnt vmcnt(3)" ::: "memory");            \
      if ((WM) == 2) asm volatile("s_waitcnt vmcnt(0)" ::: "memory");            \
      __builtin_amdgcn_s_barrier(); }      /* next slice's data published */

    // ---- prologue: stage slices 0 (slot0) and 1 (slot1); land 0 ----
    STAGE3(0, 0);
    STAGE3(1, 1);
    asm volatile("s_waitcnt vmcnt(3)" ::: "memory");
    __builtin_amdgcn_s_barrier();

    // ---- main loop: slices 0..125, staging 2..127 ----
    for (int j = 0; j < 63; ++j) {
        SLICE_PHASE(0, 1, 2 * j + 2, 1);
        SLICE_PHASE(1, 1, 2 * j + 3, 1);
    }
    // ---- tail: slices 126, 127 ----
    SLICE_PHASE(0, 0, 0, 2);   // s=126: vmcnt(0) lands slice 127
    SLICE_PHASE(1, 0, 0, 0);   // s=127: bare

#undef SLICE_PHASE
#undef STAGE3

    // ---- epilogue: bias + scatter into q/k/v regions (nontemporal) ----
    float* obase; int ldo; const float* bias; int cofs;
    if (col0 < NQ) {
        obase = out;                             ldo = NQ;  bias = bq; cofs = 0;
    } else if (col0 < NQ + NKV) {
        obase = out + (size_t)Mdim * NQ;         ldo = NKV; bias = bk; cofs = NQ;
    } else {
        obase = out + (size_t)Mdim * (NQ + NKV); ldo = NKV; bias = bv; cofs = NQ + NKV;
    }

    #pragma unroll
    for (int nf = 0; nf < 4; ++nf) {
        const int col = col0 + wn * 64 + nf * 16 + (lane & 15) - cofs;
        const float b = bias[col];
        #pragma unroll
        for (int mf = 0; mf < 4; ++mf) {
            #pragma unroll
            for (int r = 0; r < 4; ++r) {
                const int row = row0 + wm * 64 + mf * 16 + (lane >> 4) * 4 + r;
                __builtin_nontemporal_store(acc[mf][nf][r] + b,
                                            &obase[(size_t)row * ldo + col]);
            }
        }
    }
}

// ---------------------------------------------------------------------------
extern "C" void kernel_launch(void* const* d_in, const int* in_sizes, int n_in,
                              void* d_out, int out_size, void* d_ws, size_t ws_size,
                              hipStream_t stream) {
    const float* x  = (const float*)d_in[0];
    const float* Wq = (const float*)d_in[1];
    const float* Wk = (const float*)d_in[2];
    const float* Wv = (const float*)d_in[3];
    const float* bq = (const float*)d_in[4];
    const float* bk = (const float*)d_in[5];
    const float* bv = (const float*)d_in[6];
    const float* Aq = (const float*)d_in[7];
    const float* Bq = (const float*)d_in[8];
    const float* Ak = (const float*)d_in[9];
    const float* Bk = (const float*)d_in[10];
    const float* Av = (const float*)d_in[11];
    const float* Bv = (const float*)d_in[12];
    float* out = (float*)d_out;

    unsigned short* Xbf = (unsigned short*)d_ws;                   // 64 MB
    unsigned short* Wf  = Xbf + (size_t)Mdim * Kdim;               // 48 MB

    prep_kernel<<<WEFF_BLOCKS + CVT_BLOCKS, 256, 0, stream>>>(
        (const float4*)x, Xbf, Wq, Wk, Wv, Aq, Bq, Ak, Bk, Av, Bv, Wf);

    gemm_qkv_kernel<<<NWG, 512, 0, stream>>>(Xbf, Wf, bq, bk, bv, out);
}

// Round 16
// 439.078 us; speedup vs baseline: 1.0711x; 1.0711x over previous
//
#include <hip/hip_runtime.h>

// ---------------------------------------------------------------------------
// LoRA QKV fused projection on MI355X (gfx950)
// Weff-folding (LoRA into weights) + ONE bf16 MFMA GEMM + NT epilogue stores.
// R16 = R11 with ONE change: the explicit asm "s_waitcnt lgkmcnt(0)" between
//   barrier and MFMA is REMOVED. It force-drained all 8-12 ds_reads before
//   any MFMA could issue (full read/MFMA serialization — R11's measured
//   slice time == MFMA + LDS reads, serial). Frag reads are plain C++ loads:
//   the compiler emits counted lgkmcnt(N) per-MFMA (m97 behavior), letting
//   the read-burst tail complete UNDER the early MFMAs.
// Ledger: R5/R6/R9 32x32 (-8/-23/-39%), R7/R13 pre-read (-7/-10%), R8 coarse
// (-35%), R10 occupancy-via-cap (VGPR veto), R15 occupancy-via-geometry
// (2 blocks/CU reached, still slower: halved B-reuse), R12 vmcnt slack
// (neutral), R11 NT stores (+5%, kept).
// ---------------------------------------------------------------------------

#define GLOBAL_AS __attribute__((address_space(1)))
#define LDS_AS    __attribute__((address_space(3)))

typedef __attribute__((ext_vector_type(8))) short  short8;   // 8 bf16 (MFMA A/B frag)
typedef __attribute__((ext_vector_type(4))) float  floatx4;  // MFMA C/D frag

constexpr int Mdim = 8192;   // B*S
constexpr int Kdim = 4096;   // H
constexpr int NQ   = 4096;
constexpr int NKV  = 1024;
constexpr int NTOT = NQ + 2 * NKV;  // 6144
constexpr float LORA_SCALE = 2.0f;

constexpr int BM = 256, BN = 256;
constexpr int TILES_M = Mdim / BM;      // 32
constexpr int TILES_N = NTOT / BN;      // 24
constexpr int NWG = TILES_M * TILES_N;  // 768 (%8==0 -> bijective XCD swizzle)
constexpr int NSLICE = Kdim / 32;       // 128 K-slices of 32

constexpr int WEFF_BLOCKS = (NTOT / 64) * (Kdim / 512);  // 768
constexpr int CVT_BLOCKS  = 2048;
constexpr int AT_STRIDE   = 516;

__device__ __forceinline__ unsigned short f2bf(float f) {
    union { float f; unsigned int u; } a; a.f = f;
    unsigned int r = a.u + 0x7FFFu + ((a.u >> 16) & 1u);
    return (unsigned short)(r >> 16);
}

// ---------------------------------------------------------------------------
// Fused prep (identical to R4/R11):
//   blocks [0, WEFF_BLOCKS): Weff[n,h] = W[n,h] + 2*sum_r A[h,r]B[r,n] -> bf16
//   blocks [WEFF_BLOCKS, +CVT_BLOCKS): X fp32 -> bf16.
// ---------------------------------------------------------------------------
__global__ __launch_bounds__(256)
void prep_kernel(const float4* __restrict__ x4, unsigned short* __restrict__ Xbf,
                 const float* __restrict__ Wq, const float* __restrict__ Wk,
                 const float* __restrict__ Wv,
                 const float* __restrict__ Aq, const float* __restrict__ Bq,
                 const float* __restrict__ Ak, const float* __restrict__ Bk,
                 const float* __restrict__ Av, const float* __restrict__ Bv,
                 unsigned short* __restrict__ Wf) {
    __shared__ float AsT[16 * AT_STRIDE];   // ~33 KB: A^T chunk, [r][h_local]
    __shared__ float Bsc[64 * 16];          // 4 KB: 2*B[r, n0+..] as [n][r]

    const int tid = threadIdx.x;

    if (blockIdx.x >= WEFF_BLOCKS) {
        int i = (blockIdx.x - WEFF_BLOCKS) * 256 + tid;
        const int stride = CVT_BLOCKS * 256;
        const int n4 = Mdim * Kdim / 4;
        ushort4* out = (ushort4*)Xbf;
        for (; i < n4; i += stride) {
            float4 v = x4[i];
            ushort4 u;
            u.x = f2bf(v.x); u.y = f2bf(v.y); u.z = f2bf(v.z); u.w = f2bf(v.w);
            out[i] = u;
        }
        return;
    }

    const int n0 = (blockIdx.x >> 3) * 64;      // 64-row group (never straddles seg)
    const int h0 = (blockIdx.x & 7) * 512;

    const float* W; const float* A; const float* Bm; int O; int nn0;
    if (n0 < NQ)            { W = Wq; A = Aq; Bm = Bq; O = NQ;  nn0 = n0; }
    else if (n0 < NQ + NKV) { W = Wk; A = Ak; Bm = Bk; O = NKV; nn0 = n0 - NQ; }
    else                    { W = Wv; A = Av; Bm = Bv; O = NKV; nn0 = n0 - NQ - NKV; }

    {
        const float4* Af4 = (const float4*)(A) + h0 * 4;
        #pragma unroll
        for (int i = 0; i < 8; ++i) {
            const int f = i * 256 + tid;
            const float4 v = Af4[f];
            const int hl = f >> 2;
            const int r0 = (f & 3) * 4;
            AsT[(r0 + 0) * AT_STRIDE + hl] = v.x;
            AsT[(r0 + 1) * AT_STRIDE + hl] = v.y;
            AsT[(r0 + 2) * AT_STRIDE + hl] = v.z;
            AsT[(r0 + 3) * AT_STRIDE + hl] = v.w;
        }
    }
    {
        const int nl = tid & 63;
        const int rq = tid >> 6;        // 0..3
        #pragma unroll
        for (int j = 0; j < 4; ++j) {
            const int r = rq * 4 + j;
            Bsc[nl * 16 + r] = Bm[r * O + nn0 + nl] * LORA_SCALE;
        }
    }
    __syncthreads();

    const int wv_ = tid >> 6;
    const int lane = tid & 63;

    #pragma unroll
    for (int pass = 0; pass < 2; ++pass) {
        const int hl = pass * 256 + lane * 4;
        float4 areg[16];
        #pragma unroll
        for (int r = 0; r < 16; ++r)
            areg[r] = *(const float4*)(&AsT[r * AT_STRIDE + hl]);

        for (int i = 0; i < 16; ++i) {
            const int nl = wv_ * 16 + i;
            const float4 w4 = *(const float4*)(W + (size_t)(nn0 + nl) * Kdim + h0 + hl);
            const float4* b4 = (const float4*)(&Bsc[nl * 16]);
            float4 d = {0.f, 0.f, 0.f, 0.f};
            #pragma unroll
            for (int q = 0; q < 4; ++q) {
                const float4 b = b4[q];
                d.x += areg[q*4+0].x * b.x + areg[q*4+1].x * b.y + areg[q*4+2].x * b.z + areg[q*4+3].x * b.w;
                d.y += areg[q*4+0].y * b.x + areg[q*4+1].y * b.y + areg[q*4+2].y * b.z + areg[q*4+3].y * b.w;
                d.z += areg[q*4+0].z * b.x + areg[q*4+1].z * b.y + areg[q*4+2].z * b.z + areg[q*4+3].z * b.w;
                d.w += areg[q*4+0].w * b.x + areg[q*4+1].w * b.y + areg[q*4+2].w * b.z + areg[q*4+3].w * b.w;
            }
            ushort4 u;
            u.x = f2bf(w4.x + d.x); u.y = f2bf(w4.y + d.y);
            u.z = f2bf(w4.z + d.z); u.w = f2bf(w4.w + d.w);
            *(ushort4*)(Wf + (size_t)(n0 + nl) * Kdim + h0 + hl) = u;
        }
    }
}

// ---------------------------------------------------------------------------
// GEMM: out[M, NTOT] = Xbf[M,K] . Wf[NTOT,K]^T + bias, scattered to q/k/v.
// LDS: A/B rings of 4 K-slices (slice = 2 halves x 128 rows x 32 k, 16 KB).
// Schedule (8 phases per 4 slices, main loop j=0..30):
//   ph0: g0+0/Mh0, stage A(g0+3)   ph4: g0+2/Mh0, stage A(g0+5)
//   ph1: g0+0/Mh1, stage B(g0+3)   ph5: g0+2/Mh1, stage B(g0+5)
//   ph2: g0+1/Mh0, stage A(g0+4)   ph6: g0+3/Mh0, stage A(g0+6)
//   ph3: g0+1/Mh1, stage B(g0+4)   ph7: g0+3/Mh1, stage B(g0+6)
//   vmcnt(4) end of ph3/ph7. Peeled last iter (g0=124): stage only slice 127
//   at ph0/ph1; vmcnt(4) end ph3 (lands 126), vmcnt(0) end ph5 (lands 127).
// R16: NO explicit lgkmcnt(0) before the MFMA cluster — compiler emits
// counted per-MFMA lgkm waits so the read-burst tail overlaps early MFMAs.
// WAR safety unchanged: STAGE at phase p overwrites the slot whose reads
// completed before phase p-1's end barrier (compiler waits precede the
// consuming MFMAs, which precede that barrier).
// Epilogue: bias + scatter, NONTEMPORAL stores.
// ---------------------------------------------------------------------------
__global__ __launch_bounds__(512, 2)
void gemm_qkv_kernel(const unsigned short* __restrict__ X,
                     const unsigned short* __restrict__ Wf,
                     const float* __restrict__ bq, const float* __restrict__ bk,
                     const float* __restrict__ bv,
                     float* __restrict__ out) {
    __shared__ __align__(16) unsigned short Abuf[4][8192];  // 64 KB
    __shared__ __align__(16) unsigned short Bbuf[4][8192];  // 64 KB

    const int tid  = threadIdx.x;
    const int lane = tid & 63;
    const int w    = tid >> 6;
    const int wr   = w >> 2;        // 0..1  (M half)
    const int wc   = w & 3;         // 0..3  (N quarter)

    int bid = blockIdx.x;
    bid = (bid & 7) * (NWG / 8) + (bid >> 3);   // XCD-aware, bijective (768%8==0)
    const int row0 = (bid / TILES_N) * BM;
    const int col0 = (bid % TILES_N) * BN;

    const int swz    = (((lane >> 4) ^ ((lane >> 1) & 3)) << 4);    // bytes
    const int aByte0 = (wr * 128 + (lane & 15)) * 64 + swz;
    const int bByte0 = (wc * 64  + (lane & 15)) * 64 + swz;

    const int srow = (w << 4) + (lane >> 2);                         // 0..127
    const int kswz = (((lane & 3) ^ ((lane >> 3) & 3)) << 3);        // elements
    const unsigned short* pA0 = X  + (size_t)(row0 + srow) * Kdim + kswz;
    const unsigned short* pA1 = pA0 + (size_t)128 * Kdim;
    const unsigned short* pB0 = Wf + (size_t)(col0 + srow) * Kdim + kswz;
    const unsigned short* pB1 = pB0 + (size_t)128 * Kdim;

    floatx4 acc[8][4];
    #pragma unroll
    for (int i = 0; i < 8; ++i)
        #pragma unroll
        for (int j = 0; j < 4; ++j)
            acc[i][j] = (floatx4){0.f, 0.f, 0.f, 0.f};

    short8 bf[4];

#define STAGE(MATA, SS)                                                          \
    { const int ss_ = (SS); const int st_ = (SS) & 3;                            \
      if (MATA) {                                                                \
        __builtin_amdgcn_global_load_lds((const GLOBAL_AS void*)(pA0 + ss_ * 32),\
            (LDS_AS void*)(&Abuf[st_][w * 512]),        16, 0, 0);               \
        __builtin_amdgcn_global_load_lds((const GLOBAL_AS void*)(pA1 + ss_ * 32),\
            (LDS_AS void*)(&Abuf[st_][4096 + w * 512]), 16, 0, 0);               \
      } else {                                                                   \
        __builtin_amdgcn_global_load_lds((const GLOBAL_AS void*)(pB0 + ss_ * 32),\
            (LDS_AS void*)(&Bbuf[st_][w * 512]),        16, 0, 0);               \
        __builtin_amdgcn_global_load_lds((const GLOBAL_AS void*)(pB1 + ss_ * 32),\
            (LDS_AS void*)(&Bbuf[st_][4096 + w * 512]), 16, 0, 0);               \
      } }

// WAITMODE: 0 = none, 1 = vmcnt(4), 2 = vmcnt(0)
#define DO_PHASE(G, MH, DOSTAGE, SMATA, SS, WAITMODE)                            \
    {                                                                            \
      const int slot_ = (G) & 3;                                                 \
      const char* abase_ = (const char*)Abuf + slot_ * 16384;                    \
      short8 af[4];                                                              \
      _Pragma("unroll")                                                          \
      for (int mf = 0; mf < 4; ++mf)                                             \
        af[mf] = *(const short8*)(abase_ + aByte0 + ((MH) * 4 + mf) * 1024);     \
      if ((MH) == 0) {                                                           \
        const char* bbase_ = (const char*)Bbuf + slot_ * 16384;                  \
        _Pragma("unroll")                                                        \
        for (int nf = 0; nf < 4; ++nf)                                           \
          bf[nf] = *(const short8*)(bbase_ + bByte0 + nf * 1024);                \
      }                                                                          \
      if (DOSTAGE) STAGE(SMATA, SS);                                             \
      __builtin_amdgcn_s_barrier();                                              \
      /* R16: no explicit lgkmcnt(0) — compiler emits counted waits */           \
      __builtin_amdgcn_s_setprio(1);                                             \
      _Pragma("unroll")                                                          \
      for (int mf = 0; mf < 4; ++mf)                                             \
        _Pragma("unroll")                                                        \
        for (int nf = 0; nf < 4; ++nf)                                           \
          acc[(MH) * 4 + mf][nf] = __builtin_amdgcn_mfma_f32_16x16x32_bf16(      \
              af[mf], bf[nf], acc[(MH) * 4 + mf][nf], 0, 0, 0);                  \
      __builtin_amdgcn_s_setprio(0);                                             \
      if ((WAITMODE) == 1) asm volatile("s_waitcnt vmcnt(4)" ::: "memory");      \
      if ((WAITMODE) == 2) asm volatile("s_waitcnt vmcnt(0)" ::: "memory");      \
      __builtin_amdgcn_s_barrier();                                              \
    }

    // ---- prologue: stage slices 0,1,2; land 0 and 1; keep 2 in flight ----
    STAGE(1, 0); STAGE(0, 0);
    STAGE(1, 1); STAGE(0, 1);
    STAGE(1, 2); STAGE(0, 2);
    asm volatile("s_waitcnt vmcnt(4)" ::: "memory");
    __builtin_amdgcn_s_barrier();

    for (int j = 0; j < NSLICE / 4 - 1; ++j) {
        const int g0 = j * 4;
        DO_PHASE(g0 + 0, 0, 1, 1, g0 + 3, 0);
        DO_PHASE(g0 + 0, 1, 1, 0, g0 + 3, 0);
        DO_PHASE(g0 + 1, 0, 1, 1, g0 + 4, 0);
        DO_PHASE(g0 + 1, 1, 1, 0, g0 + 4, 1);
        DO_PHASE(g0 + 2, 0, 1, 1, g0 + 5, 0);
        DO_PHASE(g0 + 2, 1, 1, 0, g0 + 5, 0);
        DO_PHASE(g0 + 3, 0, 1, 1, g0 + 6, 0);
        DO_PHASE(g0 + 3, 1, 1, 0, g0 + 6, 1);
    }
    // ---- peeled last iteration (g0 = 124): stage only slice 127 ----
    DO_PHASE(124, 0, 1, 1, 127, 0);
    DO_PHASE(124, 1, 1, 0, 127, 0);
    DO_PHASE(125, 0, 0, 0, 0,   0);
    DO_PHASE(125, 1, 0, 0, 0,   1);   // lands slice 126
    DO_PHASE(126, 0, 0, 0, 0,   0);
    DO_PHASE(126, 1, 0, 0, 0,   2);   // lands slice 127
    DO_PHASE(127, 0, 0, 0, 0,   0);
    DO_PHASE(127, 1, 0, 0, 0,   0);

#undef DO_PHASE
#undef STAGE

    // ---- epilogue: bias + scatter into q/k/v regions (nontemporal) ----
    float* obase; int ldo; const float* bias; int cofs;
    if (col0 < NQ) {
        obase = out;                             ldo = NQ;  bias = bq; cofs = 0;
    } else if (col0 < NQ + NKV) {
        obase = out + (size_t)Mdim * NQ;         ldo = NKV; bias = bk; cofs = NQ;
    } else {
        obase = out + (size_t)Mdim * (NQ + NKV); ldo = NKV; bias = bv; cofs = NQ + NKV;
    }

    #pragma unroll
    for (int nf = 0; nf < 4; ++nf) {
        const int col = col0 + wc * 64 + nf * 16 + (lane & 15) - cofs;
        const float b = bias[col];
        #pragma unroll
        for (int mf = 0; mf < 8; ++mf) {
            #pragma unroll
            for (int r = 0; r < 4; ++r) {
                const int row = row0 + wr * 128 + mf * 16 + (lane >> 4) * 4 + r;
                __builtin_nontemporal_store(acc[mf][nf][r] + b,
                                            &obase[(size_t)row * ldo + col]);
            }
        }
    }
}

// ---------------------------------------------------------------------------
extern "C" void kernel_launch(void* const* d_in, const int* in_sizes, int n_in,
                              void* d_out, int out_size, void* d_ws, size_t ws_size,
                              hipStream_t stream) {
    const float* x  = (const float*)d_in[0];
    const float* Wq = (const float*)d_in[1];
    const float* Wk = (const float*)d_in[2];
    const float* Wv = (const float*)d_in[3];
    const float* bq = (const float*)d_in[4];
    const float* bk = (const float*)d_in[5];
    const float* bv = (const float*)d_in[6];
    const float* Aq = (const float*)d_in[7];
    const float* Bq = (const float*)d_in[8];
    const float* Ak = (const float*)d_in[9];
    const float* Bk = (const float*)d_in[10];
    const float* Av = (const float*)d_in[11];
    const float* Bv = (const float*)d_in[12];
    float* out = (float*)d_out;

    unsigned short* Xbf = (unsigned short*)d_ws;                   // 64 MB
    unsigned short* Wf  = Xbf + (size_t)Mdim * Kdim;               // 48 MB

    prep_kernel<<<WEFF_BLOCKS + CVT_BLOCKS, 256, 0, stream>>>(
        (const float4*)x, Xbf, Wq, Wk, Wv, Aq, Bq, Ak, Bk, Av, Bv, Wf);

    gemm_qkv_kernel<<<NWG, 512, 0, stream>>>(Xbf, Wf, bq, bk, bv, out);
}

// Round 17
// 434.266 us; speedup vs baseline: 1.0829x; 1.0111x over previous
//
#include <hip/hip_runtime.h>

// ---------------------------------------------------------------------------
// LoRA QKV fused projection on MI355X (gfx950)
// Weff-folding (LoRA into weights) + ONE bf16 MFMA GEMM + NT epilogue stores.
// R17 = R14 (best stable config) made PERSISTENT: grid = 256 blocks, each
//   computes 3 consecutive N-tiles of one M-row (A-panel L2 reuse; 24%3==0
//   so a triple never crosses rows). Transition between tiles:
//     epilogue(t) stores -> STAGE x6 for t+1 -> vmcnt(4) -> barrier
//   vmcnt retires IN ORDER, so vmcnt(4) (keeping slice-2's 4 loads) retires
//   ALL prior stores + slices 0,1 — exactly the R11/R14 prologue guarantee —
//   while the store drain overlaps the prologue-load flight instead of
//   blocking s_endpgm (the old per-block ~8-10us serial drain, paid x3).
//   In-loop schedule, swizzles, and ledger are R14-verbatim.
// Ledger: R5/R6/R9 32x32 (-8/-23/-39%), R7/R13 pre-read (-7/-10%), R8 coarse
// (-35%), R10/R15 occupancy (veto / slower), R12 loose vmcnt (neutral),
// R16 no-lgkm-drain (neutral), R11 NT stores (+5%, kept).
// ---------------------------------------------------------------------------

#define GLOBAL_AS __attribute__((address_space(1)))
#define LDS_AS    __attribute__((address_space(3)))

typedef __attribute__((ext_vector_type(8))) short  short8;   // 8 bf16 (MFMA A/B frag)
typedef __attribute__((ext_vector_type(4))) float  floatx4;  // MFMA C/D frag

constexpr int Mdim = 8192;   // B*S
constexpr int Kdim = 4096;   // H
constexpr int NQ   = 4096;
constexpr int NKV  = 1024;
constexpr int NTOT = NQ + 2 * NKV;  // 6144
constexpr float LORA_SCALE = 2.0f;

constexpr int BM = 256, BN = 256;
constexpr int TILES_M = Mdim / BM;      // 32
constexpr int TILES_N = NTOT / BN;      // 24
constexpr int NWG = 256;                // persistent: 3 tiles per block
constexpr int NSLICE = Kdim / 32;       // 128 K-slices of 32

constexpr int WEFF_BLOCKS = (NTOT / 64) * (Kdim / 512);  // 768
constexpr int CVT_BLOCKS  = 2048;
constexpr int AT_STRIDE   = 516;

__device__ __forceinline__ unsigned short f2bf(float f) {
    union { float f; unsigned int u; } a; a.f = f;
    unsigned int r = a.u + 0x7FFFu + ((a.u >> 16) & 1u);
    return (unsigned short)(r >> 16);
}

// ---------------------------------------------------------------------------
// Fused prep (identical to R4/R11):
//   blocks [0, WEFF_BLOCKS): Weff[n,h] = W[n,h] + 2*sum_r A[h,r]B[r,n] -> bf16
//   blocks [WEFF_BLOCKS, +CVT_BLOCKS): X fp32 -> bf16.
// ---------------------------------------------------------------------------
__global__ __launch_bounds__(256)
void prep_kernel(const float4* __restrict__ x4, unsigned short* __restrict__ Xbf,
                 const float* __restrict__ Wq, const float* __restrict__ Wk,
                 const float* __restrict__ Wv,
                 const float* __restrict__ Aq, const float* __restrict__ Bq,
                 const float* __restrict__ Ak, const float* __restrict__ Bk,
                 const float* __restrict__ Av, const float* __restrict__ Bv,
                 unsigned short* __restrict__ Wf) {
    __shared__ float AsT[16 * AT_STRIDE];   // ~33 KB: A^T chunk, [r][h_local]
    __shared__ float Bsc[64 * 16];          // 4 KB: 2*B[r, n0+..] as [n][r]

    const int tid = threadIdx.x;

    if (blockIdx.x >= WEFF_BLOCKS) {
        int i = (blockIdx.x - WEFF_BLOCKS) * 256 + tid;
        const int stride = CVT_BLOCKS * 256;
        const int n4 = Mdim * Kdim / 4;
        ushort4* out = (ushort4*)Xbf;
        for (; i < n4; i += stride) {
            float4 v = x4[i];
            ushort4 u;
            u.x = f2bf(v.x); u.y = f2bf(v.y); u.z = f2bf(v.z); u.w = f2bf(v.w);
            out[i] = u;
        }
        return;
    }

    const int n0 = (blockIdx.x >> 3) * 64;      // 64-row group (never straddles seg)
    const int h0 = (blockIdx.x & 7) * 512;

    const float* W; const float* A; const float* Bm; int O; int nn0;
    if (n0 < NQ)            { W = Wq; A = Aq; Bm = Bq; O = NQ;  nn0 = n0; }
    else if (n0 < NQ + NKV) { W = Wk; A = Ak; Bm = Bk; O = NKV; nn0 = n0 - NQ; }
    else                    { W = Wv; A = Av; Bm = Bv; O = NKV; nn0 = n0 - NQ - NKV; }

    {
        const float4* Af4 = (const float4*)(A) + h0 * 4;
        #pragma unroll
        for (int i = 0; i < 8; ++i) {
            const int f = i * 256 + tid;
            const float4 v = Af4[f];
            const int hl = f >> 2;
            const int r0 = (f & 3) * 4;
            AsT[(r0 + 0) * AT_STRIDE + hl] = v.x;
            AsT[(r0 + 1) * AT_STRIDE + hl] = v.y;
            AsT[(r0 + 2) * AT_STRIDE + hl] = v.z;
            AsT[(r0 + 3) * AT_STRIDE + hl] = v.w;
        }
    }
    {
        const int nl = tid & 63;
        const int rq = tid >> 6;        // 0..3
        #pragma unroll
        for (int j = 0; j < 4; ++j) {
            const int r = rq * 4 + j;
            Bsc[nl * 16 + r] = Bm[r * O + nn0 + nl] * LORA_SCALE;
        }
    }
    __syncthreads();

    const int wv_ = tid >> 6;
    const int lane = tid & 63;

    #pragma unroll
    for (int pass = 0; pass < 2; ++pass) {
        const int hl = pass * 256 + lane * 4;
        float4 areg[16];
        #pragma unroll
        for (int r = 0; r < 16; ++r)
            areg[r] = *(const float4*)(&AsT[r * AT_STRIDE + hl]);

        for (int i = 0; i < 16; ++i) {
            const int nl = wv_ * 16 + i;
            const float4 w4 = *(const float4*)(W + (size_t)(nn0 + nl) * Kdim + h0 + hl);
            const float4* b4 = (const float4*)(&Bsc[nl * 16]);
            float4 d = {0.f, 0.f, 0.f, 0.f};
            #pragma unroll
            for (int q = 0; q < 4; ++q) {
                const float4 b = b4[q];
                d.x += areg[q*4+0].x * b.x + areg[q*4+1].x * b.y + areg[q*4+2].x * b.z + areg[q*4+3].x * b.w;
                d.y += areg[q*4+0].y * b.x + areg[q*4+1].y * b.y + areg[q*4+2].y * b.z + areg[q*4+3].y * b.w;
                d.z += areg[q*4+0].z * b.x + areg[q*4+1].z * b.y + areg[q*4+2].z * b.z + areg[q*4+3].z * b.w;
                d.w += areg[q*4+0].w * b.x + areg[q*4+1].w * b.y + areg[q*4+2].w * b.z + areg[q*4+3].w * b.w;
            }
            ushort4 u;
            u.x = f2bf(w4.x + d.x); u.y = f2bf(w4.y + d.y);
            u.z = f2bf(w4.z + d.z); u.w = f2bf(w4.w + d.w);
            *(ushort4*)(Wf + (size_t)(n0 + nl) * Kdim + h0 + hl) = u;
        }
    }
}

// ---------------------------------------------------------------------------
// GEMM (persistent): each block computes 3 tiles (one M-row, 3 consecutive
// N-tiles). Per tile: R14-verbatim K-loop (2 phases/slice, vmcnt(4) at
// ph3/ph7, setprio, lgkmcnt(0), 16-B-chunk swizzle, conflicts=0) + NT
// epilogue. Tile transition: epilogue stores -> STAGE x6 -> vmcnt(4) ->
// barrier (in-order retire => stores drained + slices 0,1 landed).
// ---------------------------------------------------------------------------
__global__ __launch_bounds__(512, 2)
void gemm_qkv_kernel(const unsigned short* __restrict__ X,
                     const unsigned short* __restrict__ Wf,
                     const float* __restrict__ bq, const float* __restrict__ bk,
                     const float* __restrict__ bv,
                     float* __restrict__ out) {
    __shared__ __align__(16) unsigned short Abuf[4][8192];  // 64 KB
    __shared__ __align__(16) unsigned short Bbuf[4][8192];  // 64 KB

    const int tid  = threadIdx.x;
    const int lane = tid & 63;
    const int w    = tid >> 6;
    const int wr   = w >> 2;        // 0..1  (M half)
    const int wc   = w & 3;         // 0..3  (N quarter)

    // XCD-aware persistent mapping: physical block q -> swizzled qs; tiles
    // qs*3 + t (t=0..2) = one M-row, 3 consecutive N-tiles (24 % 3 == 0).
    const int qs = (blockIdx.x & 7) * 32 + (blockIdx.x >> 3);

    const int swz    = (((lane >> 4) ^ ((lane >> 1) & 3)) << 4);    // bytes
    const int aByte0 = (wr * 128 + (lane & 15)) * 64 + swz;
    const int bByte0 = (wc * 64  + (lane & 15)) * 64 + swz;

    const int srow = (w << 4) + (lane >> 2);                         // 0..127
    const int kswz = (((lane & 3) ^ ((lane >> 3) & 3)) << 3);        // elements

    const unsigned short* pA0; const unsigned short* pA1;
    const unsigned short* pB0; const unsigned short* pB1;

    floatx4 acc[8][4];
    short8 bf[4];

#define STAGE(MATA, SS)                                                          \
    { const int ss_ = (SS); const int st_ = (SS) & 3;                            \
      if (MATA) {                                                                \
        __builtin_amdgcn_global_load_lds((const GLOBAL_AS void*)(pA0 + ss_ * 32),\
            (LDS_AS void*)(&Abuf[st_][w * 512]),        16, 0, 0);               \
        __builtin_amdgcn_global_load_lds((const GLOBAL_AS void*)(pA1 + ss_ * 32),\
            (LDS_AS void*)(&Abuf[st_][4096 + w * 512]), 16, 0, 0);               \
      } else {                                                                   \
        __builtin_amdgcn_global_load_lds((const GLOBAL_AS void*)(pB0 + ss_ * 32),\
            (LDS_AS void*)(&Bbuf[st_][w * 512]),        16, 0, 0);               \
        __builtin_amdgcn_global_load_lds((const GLOBAL_AS void*)(pB1 + ss_ * 32),\
            (LDS_AS void*)(&Bbuf[st_][4096 + w * 512]), 16, 0, 0);               \
      } }

// WAITMODE: 0 = none, 1 = vmcnt(4), 2 = vmcnt(0)
#define DO_PHASE(G, MH, DOSTAGE, SMATA, SS, WAITMODE)                            \
    {                                                                            \
      const int slot_ = (G) & 3;                                                 \
      const char* abase_ = (const char*)Abuf + slot_ * 16384;                    \
      short8 af[4];                                                              \
      _Pragma("unroll")                                                          \
      for (int mf = 0; mf < 4; ++mf)                                             \
        af[mf] = *(const short8*)(abase_ + aByte0 + ((MH) * 4 + mf) * 1024);     \
      if ((MH) == 0) {                                                           \
        const char* bbase_ = (const char*)Bbuf + slot_ * 16384;                  \
        _Pragma("unroll")                                                        \
        for (int nf = 0; nf < 4; ++nf)                                           \
          bf[nf] = *(const short8*)(bbase_ + bByte0 + nf * 1024);                \
      }                                                                          \
      if (DOSTAGE) STAGE(SMATA, SS);                                             \
      __builtin_amdgcn_s_barrier();                                              \
      asm volatile("s_waitcnt lgkmcnt(0)");                                      \
      __builtin_amdgcn_s_setprio(1);                                             \
      _Pragma("unroll")                                                          \
      for (int mf = 0; mf < 4; ++mf)                                             \
        _Pragma("unroll")                                                        \
        for (int nf = 0; nf < 4; ++nf)                                           \
          acc[(MH) * 4 + mf][nf] = __builtin_amdgcn_mfma_f32_16x16x32_bf16(      \
              af[mf], bf[nf], acc[(MH) * 4 + mf][nf], 0, 0, 0);                  \
      __builtin_amdgcn_s_setprio(0);                                             \
      if ((WAITMODE) == 1) asm volatile("s_waitcnt vmcnt(4)" ::: "memory");      \
      if ((WAITMODE) == 2) asm volatile("s_waitcnt vmcnt(0)" ::: "memory");      \
      __builtin_amdgcn_s_barrier();                                              \
    }

    for (int t = 0; t < 3; ++t) {
        const int tile = qs * 3 + t;
        const int row0 = (tile / TILES_N) * BM;
        const int col0 = (tile % TILES_N) * BN;

        pA0 = X  + (size_t)(row0 + srow) * Kdim + kswz;
        pA1 = pA0 + (size_t)128 * Kdim;
        pB0 = Wf + (size_t)(col0 + srow) * Kdim + kswz;
        pB1 = pB0 + (size_t)128 * Kdim;

        #pragma unroll
        for (int i = 0; i < 8; ++i)
            #pragma unroll
            for (int j = 0; j < 4; ++j)
                acc[i][j] = (floatx4){0.f, 0.f, 0.f, 0.f};

        // ---- prologue: stage slices 0,1,2. vmcnt(4) retires (in order) all
        // prior-tile stores + slices 0,1; slice 2's 4 loads stay in flight —
        // identical guarantee to the R11/R14 prologue. ----
        STAGE(1, 0); STAGE(0, 0);
        STAGE(1, 1); STAGE(0, 1);
        STAGE(1, 2); STAGE(0, 2);
        asm volatile("s_waitcnt vmcnt(4)" ::: "memory");
        __builtin_amdgcn_s_barrier();

        for (int j = 0; j < NSLICE / 4 - 1; ++j) {
            const int g0 = j * 4;
            DO_PHASE(g0 + 0, 0, 1, 1, g0 + 3, 0);
            DO_PHASE(g0 + 0, 1, 1, 0, g0 + 3, 0);
            DO_PHASE(g0 + 1, 0, 1, 1, g0 + 4, 0);
            DO_PHASE(g0 + 1, 1, 1, 0, g0 + 4, 1);
            DO_PHASE(g0 + 2, 0, 1, 1, g0 + 5, 0);
            DO_PHASE(g0 + 2, 1, 1, 0, g0 + 5, 0);
            DO_PHASE(g0 + 3, 0, 1, 1, g0 + 6, 0);
            DO_PHASE(g0 + 3, 1, 1, 0, g0 + 6, 1);
        }
        // ---- peeled last iteration (g0 = 124): stage only slice 127 ----
        DO_PHASE(124, 0, 1, 1, 127, 0);
        DO_PHASE(124, 1, 1, 0, 127, 0);
        DO_PHASE(125, 0, 0, 0, 0,   0);
        DO_PHASE(125, 1, 0, 0, 0,   1);   // lands slice 126
        DO_PHASE(126, 0, 0, 0, 0,   0);
        DO_PHASE(126, 1, 0, 0, 0,   2);   // lands slice 127
        DO_PHASE(127, 0, 0, 0, 0,   0);
        DO_PHASE(127, 1, 0, 0, 0,   0);

        // ---- epilogue: bias + scatter (NT stores; drained by next tile's
        // prologue vmcnt(4) or by the implicit end-of-kernel wait) ----
        float* obase; int ldo; const float* bias; int cofs;
        if (col0 < NQ) {
            obase = out;                             ldo = NQ;  bias = bq; cofs = 0;
        } else if (col0 < NQ + NKV) {
            obase = out + (size_t)Mdim * NQ;         ldo = NKV; bias = bk; cofs = NQ;
        } else {
            obase = out + (size_t)Mdim * (NQ + NKV); ldo = NKV; bias = bv; cofs = NQ + NKV;
        }

        #pragma unroll
        for (int nf = 0; nf < 4; ++nf) {
            const int col = col0 + wc * 64 + nf * 16 + (lane & 15) - cofs;
            const float b = bias[col];
            #pragma unroll
            for (int mf = 0; mf < 8; ++mf) {
                #pragma unroll
                for (int r = 0; r < 4; ++r) {
                    const int row = row0 + wr * 128 + mf * 16 + (lane >> 4) * 4 + r;
                    __builtin_nontemporal_store(acc[mf][nf][r] + b,
                                                &obase[(size_t)row * ldo + col]);
                }
            }
        }
    }

#undef DO_PHASE
#undef STAGE
}

// ---------------------------------------------------------------------------
extern "C" void kernel_launch(void* const* d_in, const int* in_sizes, int n_in,
                              void* d_out, int out_size, void* d_ws, size_t ws_size,
                              hipStream_t stream) {
    const float* x  = (const float*)d_in[0];
    const float* Wq = (const float*)d_in[1];
    const float* Wk = (const float*)d_in[2];
    const float* Wv = (const float*)d_in[3];
    const float* bq = (const float*)d_in[4];
    const float* bk = (const float*)d_in[5];
    const float* bv = (const float*)d_in[6];
    const float* Aq = (const float*)d_in[7];
    const float* Bq = (const float*)d_in[8];
    const float* Ak = (const float*)d_in[9];
    const float* Bk = (const float*)d_in[10];
    const float* Av = (const float*)d_in[11];
    const float* Bv = (const float*)d_in[12];
    float* out = (float*)d_out;

    unsigned short* Xbf = (unsigned short*)d_ws;                   // 64 MB
    unsigned short* Wf  = Xbf + (size_t)Mdim * Kdim;               // 48 MB

    prep_kernel<<<WEFF_BLOCKS + CVT_BLOCKS, 256, 0, stream>>>(
        (const float4*)x, Xbf, Wq, Wk, Wv, Aq, Bq, Ak, Bk, Av, Bv, Wf);

    gemm_qkv_kernel<<<NWG, 512, 0, stream>>>(Xbf, Wf, bq, bk, bv, out);
}

// Round 18
// 429.664 us; speedup vs baseline: 1.0945x; 1.0107x over previous
//
#include <hip/hip_runtime.h>

// ---------------------------------------------------------------------------
// LoRA QKV fused projection on MI355X (gfx950)  — FINAL CANDIDATE (R17 lock-in)
// Weff-folding (LoRA into weights) + ONE bf16 MFMA GEMM + NT epilogue stores,
// persistent blocks (256 blocks x 3 N-tiles of one M-row; A-panel L2 reuse).
//
// Search ledger (13 variants, all single-variable where possible):
//   R5/R6/R9 32x32 frags: -8/-23/-39%   R7/R13 reg pre-read: -7/-10%
//   R8 coarse phases: -35%              R10/R15 occupancy: veto / slower
//   R12 loose vmcnt: neutral            R16 no-lgkm-drain: neutral
//   R11 NT stores: +5% (kept)           R17 persistent: FETCH halved, best total
// Plateau: GEMM ~1030 TF (41% dense), MfmaUtil ~45-50%, conflicts 0, HBM 18-33%
// — sync-structural local optimum; every structural escape regressed.
// ---------------------------------------------------------------------------

#define GLOBAL_AS __attribute__((address_space(1)))
#define LDS_AS    __attribute__((address_space(3)))

typedef __attribute__((ext_vector_type(8))) short  short8;   // 8 bf16 (MFMA A/B frag)
typedef __attribute__((ext_vector_type(4))) float  floatx4;  // MFMA C/D frag

constexpr int Mdim = 8192;   // B*S
constexpr int Kdim = 4096;   // H
constexpr int NQ   = 4096;
constexpr int NKV  = 1024;
constexpr int NTOT = NQ + 2 * NKV;  // 6144
constexpr float LORA_SCALE = 2.0f;

constexpr int BM = 256, BN = 256;
constexpr int TILES_M = Mdim / BM;      // 32
constexpr int TILES_N = NTOT / BN;      // 24
constexpr int NWG = 256;                // persistent: 3 tiles per block
constexpr int NSLICE = Kdim / 32;       // 128 K-slices of 32

constexpr int WEFF_BLOCKS = (NTOT / 64) * (Kdim / 512);  // 768
constexpr int CVT_BLOCKS  = 2048;
constexpr int AT_STRIDE   = 516;

__device__ __forceinline__ unsigned short f2bf(float f) {
    union { float f; unsigned int u; } a; a.f = f;
    unsigned int r = a.u + 0x7FFFu + ((a.u >> 16) & 1u);
    return (unsigned short)(r >> 16);
}

// ---------------------------------------------------------------------------
// Fused prep:
//   blocks [0, WEFF_BLOCKS): Weff[n,h] = W[n,h] + 2*sum_r A[h,r]B[r,n] -> bf16
//   blocks [WEFF_BLOCKS, +CVT_BLOCKS): X fp32 -> bf16.
// ---------------------------------------------------------------------------
__global__ __launch_bounds__(256)
void prep_kernel(const float4* __restrict__ x4, unsigned short* __restrict__ Xbf,
                 const float* __restrict__ Wq, const float* __restrict__ Wk,
                 const float* __restrict__ Wv,
                 const float* __restrict__ Aq, const float* __restrict__ Bq,
                 const float* __restrict__ Ak, const float* __restrict__ Bk,
                 const float* __restrict__ Av, const float* __restrict__ Bv,
                 unsigned short* __restrict__ Wf) {
    __shared__ float AsT[16 * AT_STRIDE];   // ~33 KB: A^T chunk, [r][h_local]
    __shared__ float Bsc[64 * 16];          // 4 KB: 2*B[r, n0+..] as [n][r]

    const int tid = threadIdx.x;

    if (blockIdx.x >= WEFF_BLOCKS) {
        int i = (blockIdx.x - WEFF_BLOCKS) * 256 + tid;
        const int stride = CVT_BLOCKS * 256;
        const int n4 = Mdim * Kdim / 4;
        ushort4* out = (ushort4*)Xbf;
        for (; i < n4; i += stride) {
            float4 v = x4[i];
            ushort4 u;
            u.x = f2bf(v.x); u.y = f2bf(v.y); u.z = f2bf(v.z); u.w = f2bf(v.w);
            out[i] = u;
        }
        return;
    }

    const int n0 = (blockIdx.x >> 3) * 64;      // 64-row group (never straddles seg)
    const int h0 = (blockIdx.x & 7) * 512;

    const float* W; const float* A; const float* Bm; int O; int nn0;
    if (n0 < NQ)            { W = Wq; A = Aq; Bm = Bq; O = NQ;  nn0 = n0; }
    else if (n0 < NQ + NKV) { W = Wk; A = Ak; Bm = Bk; O = NKV; nn0 = n0 - NQ; }
    else                    { W = Wv; A = Av; Bm = Bv; O = NKV; nn0 = n0 - NQ - NKV; }

    {
        const float4* Af4 = (const float4*)(A) + h0 * 4;
        #pragma unroll
        for (int i = 0; i < 8; ++i) {
            const int f = i * 256 + tid;
            const float4 v = Af4[f];
            const int hl = f >> 2;
            const int r0 = (f & 3) * 4;
            AsT[(r0 + 0) * AT_STRIDE + hl] = v.x;
            AsT[(r0 + 1) * AT_STRIDE + hl] = v.y;
            AsT[(r0 + 2) * AT_STRIDE + hl] = v.z;
            AsT[(r0 + 3) * AT_STRIDE + hl] = v.w;
        }
    }
    {
        const int nl = tid & 63;
        const int rq = tid >> 6;        // 0..3
        #pragma unroll
        for (int j = 0; j < 4; ++j) {
            const int r = rq * 4 + j;
            Bsc[nl * 16 + r] = Bm[r * O + nn0 + nl] * LORA_SCALE;
        }
    }
    __syncthreads();

    const int wv_ = tid >> 6;
    const int lane = tid & 63;

    #pragma unroll
    for (int pass = 0; pass < 2; ++pass) {
        const int hl = pass * 256 + lane * 4;
        float4 areg[16];
        #pragma unroll
        for (int r = 0; r < 16; ++r)
            areg[r] = *(const float4*)(&AsT[r * AT_STRIDE + hl]);

        for (int i = 0; i < 16; ++i) {
            const int nl = wv_ * 16 + i;
            const float4 w4 = *(const float4*)(W + (size_t)(nn0 + nl) * Kdim + h0 + hl);
            const float4* b4 = (const float4*)(&Bsc[nl * 16]);
            float4 d = {0.f, 0.f, 0.f, 0.f};
            #pragma unroll
            for (int q = 0; q < 4; ++q) {
                const float4 b = b4[q];
                d.x += areg[q*4+0].x * b.x + areg[q*4+1].x * b.y + areg[q*4+2].x * b.z + areg[q*4+3].x * b.w;
                d.y += areg[q*4+0].y * b.x + areg[q*4+1].y * b.y + areg[q*4+2].y * b.z + areg[q*4+3].y * b.w;
                d.z += areg[q*4+0].z * b.x + areg[q*4+1].z * b.y + areg[q*4+2].z * b.z + areg[q*4+3].z * b.w;
                d.w += areg[q*4+0].w * b.x + areg[q*4+1].w * b.y + areg[q*4+2].w * b.z + areg[q*4+3].w * b.w;
            }
            ushort4 u;
            u.x = f2bf(w4.x + d.x); u.y = f2bf(w4.y + d.y);
            u.z = f2bf(w4.z + d.z); u.w = f2bf(w4.w + d.w);
            *(ushort4*)(Wf + (size_t)(n0 + nl) * Kdim + h0 + hl) = u;
        }
    }
}

// ---------------------------------------------------------------------------
// GEMM (persistent): each block computes 3 tiles (one M-row, 3 consecutive
// N-tiles). Per tile: 2 phases/slice, vmcnt(4) at ph3/ph7, setprio,
// lgkmcnt(0), 16-B-chunk swizzle (conflicts=0) + NT epilogue. Tile
// transition: epilogue stores -> STAGE x6 -> vmcnt(4) -> barrier (in-order
// retire => stores drained + slices 0,1 landed).
// ---------------------------------------------------------------------------
__global__ __launch_bounds__(512, 2)
void gemm_qkv_kernel(const unsigned short* __restrict__ X,
                     const unsigned short* __restrict__ Wf,
                     const float* __restrict__ bq, const float* __restrict__ bk,
                     const float* __restrict__ bv,
                     float* __restrict__ out) {
    __shared__ __align__(16) unsigned short Abuf[4][8192];  // 64 KB
    __shared__ __align__(16) unsigned short Bbuf[4][8192];  // 64 KB

    const int tid  = threadIdx.x;
    const int lane = tid & 63;
    const int w    = tid >> 6;
    const int wr   = w >> 2;        // 0..1  (M half)
    const int wc   = w & 3;         // 0..3  (N quarter)

    const int qs = (blockIdx.x & 7) * 32 + (blockIdx.x >> 3);

    const int swz    = (((lane >> 4) ^ ((lane >> 1) & 3)) << 4);    // bytes
    const int aByte0 = (wr * 128 + (lane & 15)) * 64 + swz;
    const int bByte0 = (wc * 64  + (lane & 15)) * 64 + swz;

    const int srow = (w << 4) + (lane >> 2);                         // 0..127
    const int kswz = (((lane & 3) ^ ((lane >> 3) & 3)) << 3);        // elements

    const unsigned short* pA0; const unsigned short* pA1;
    const unsigned short* pB0; const unsigned short* pB1;

    floatx4 acc[8][4];
    short8 bf[4];

#define STAGE(MATA, SS)                                                          \
    { const int ss_ = (SS); const int st_ = (SS) & 3;                            \
      if (MATA) {                                                                \
        __builtin_amdgcn_global_load_lds((const GLOBAL_AS void*)(pA0 + ss_ * 32),\
            (LDS_AS void*)(&Abuf[st_][w * 512]),        16, 0, 0);               \
        __builtin_amdgcn_global_load_lds((const GLOBAL_AS void*)(pA1 + ss_ * 32),\
            (LDS_AS void*)(&Abuf[st_][4096 + w * 512]), 16, 0, 0);               \
      } else {                                                                   \
        __builtin_amdgcn_global_load_lds((const GLOBAL_AS void*)(pB0 + ss_ * 32),\
            (LDS_AS void*)(&Bbuf[st_][w * 512]),        16, 0, 0);               \
        __builtin_amdgcn_global_load_lds((const GLOBAL_AS void*)(pB1 + ss_ * 32),\
            (LDS_AS void*)(&Bbuf[st_][4096 + w * 512]), 16, 0, 0);               \
      } }

// WAITMODE: 0 = none, 1 = vmcnt(4), 2 = vmcnt(0)
#define DO_PHASE(G, MH, DOSTAGE, SMATA, SS, WAITMODE)                            \
    {                                                                            \
      const int slot_ = (G) & 3;                                                 \
      const char* abase_ = (const char*)Abuf + slot_ * 16384;                    \
      short8 af[4];                                                              \
      _Pragma("unroll")                                                          \
      for (int mf = 0; mf < 4; ++mf)                                             \
        af[mf] = *(const short8*)(abase_ + aByte0 + ((MH) * 4 + mf) * 1024);     \
      if ((MH) == 0) {                                                           \
        const char* bbase_ = (const char*)Bbuf + slot_ * 16384;                  \
        _Pragma("unroll")                                                        \
        for (int nf = 0; nf < 4; ++nf)                                           \
          bf[nf] = *(const short8*)(bbase_ + bByte0 + nf * 1024);                \
      }                                                                          \
      if (DOSTAGE) STAGE(SMATA, SS);                                             \
      __builtin_amdgcn_s_barrier();                                              \
      asm volatile("s_waitcnt lgkmcnt(0)");                                      \
      __builtin_amdgcn_s_setprio(1);                                             \
      _Pragma("unroll")                                                          \
      for (int mf = 0; mf < 4; ++mf)                                             \
        _Pragma("unroll")                                                        \
        for (int nf = 0; nf < 4; ++nf)                                           \
          acc[(MH) * 4 + mf][nf] = __builtin_amdgcn_mfma_f32_16x16x32_bf16(      \
              af[mf], bf[nf], acc[(MH) * 4 + mf][nf], 0, 0, 0);                  \
      __builtin_amdgcn_s_setprio(0);                                             \
      if ((WAITMODE) == 1) asm volatile("s_waitcnt vmcnt(4)" ::: "memory");      \
      if ((WAITMODE) == 2) asm volatile("s_waitcnt vmcnt(0)" ::: "memory");      \
      __builtin_amdgcn_s_barrier();                                              \
    }

    for (int t = 0; t < 3; ++t) {
        const int tile = qs * 3 + t;
        const int row0 = (tile / TILES_N) * BM;
        const int col0 = (tile % TILES_N) * BN;

        pA0 = X  + (size_t)(row0 + srow) * Kdim + kswz;
        pA1 = pA0 + (size_t)128 * Kdim;
        pB0 = Wf + (size_t)(col0 + srow) * Kdim + kswz;
        pB1 = pB0 + (size_t)128 * Kdim;

        #pragma unroll
        for (int i = 0; i < 8; ++i)
            #pragma unroll
            for (int j = 0; j < 4; ++j)
                acc[i][j] = (floatx4){0.f, 0.f, 0.f, 0.f};

        // ---- prologue: stage slices 0,1,2. vmcnt(4) retires (in order) all
        // prior-tile stores + slices 0,1; slice 2 stays in flight. ----
        STAGE(1, 0); STAGE(0, 0);
        STAGE(1, 1); STAGE(0, 1);
        STAGE(1, 2); STAGE(0, 2);
        asm volatile("s_waitcnt vmcnt(4)" ::: "memory");
        __builtin_amdgcn_s_barrier();

        for (int j = 0; j < NSLICE / 4 - 1; ++j) {
            const int g0 = j * 4;
            DO_PHASE(g0 + 0, 0, 1, 1, g0 + 3, 0);
            DO_PHASE(g0 + 0, 1, 1, 0, g0 + 3, 0);
            DO_PHASE(g0 + 1, 0, 1, 1, g0 + 4, 0);
            DO_PHASE(g0 + 1, 1, 1, 0, g0 + 4, 1);
            DO_PHASE(g0 + 2, 0, 1, 1, g0 + 5, 0);
            DO_PHASE(g0 + 2, 1, 1, 0, g0 + 5, 0);
            DO_PHASE(g0 + 3, 0, 1, 1, g0 + 6, 0);
            DO_PHASE(g0 + 3, 1, 1, 0, g0 + 6, 1);
        }
        // ---- peeled last iteration (g0 = 124): stage only slice 127 ----
        DO_PHASE(124, 0, 1, 1, 127, 0);
        DO_PHASE(124, 1, 1, 0, 127, 0);
        DO_PHASE(125, 0, 0, 0, 0,   0);
        DO_PHASE(125, 1, 0, 0, 0,   1);   // lands slice 126
        DO_PHASE(126, 0, 0, 0, 0,   0);
        DO_PHASE(126, 1, 0, 0, 0,   2);   // lands slice 127
        DO_PHASE(127, 0, 0, 0, 0,   0);
        DO_PHASE(127, 1, 0, 0, 0,   0);

        // ---- epilogue: bias + scatter (NT stores; drained by next tile's
        // prologue vmcnt(4) or the end-of-kernel wait) ----
        float* obase; int ldo; const float* bias; int cofs;
        if (col0 < NQ) {
            obase = out;                             ldo = NQ;  bias = bq; cofs = 0;
        } else if (col0 < NQ + NKV) {
            obase = out + (size_t)Mdim * NQ;         ldo = NKV; bias = bk; cofs = NQ;
        } else {
            obase = out + (size_t)Mdim * (NQ + NKV); ldo = NKV; bias = bv; cofs = NQ + NKV;
        }

        #pragma unroll
        for (int nf = 0; nf < 4; ++nf) {
            const int col = col0 + wc * 64 + nf * 16 + (lane & 15) - cofs;
            const float b = bias[col];
            #pragma unroll
            for (int mf = 0; mf < 8; ++mf) {
                #pragma unroll
                for (int r = 0; r < 4; ++r) {
                    const int row = row0 + wr * 128 + mf * 16 + (lane >> 4) * 4 + r;
                    __builtin_nontemporal_store(acc[mf][nf][r] + b,
                                                &obase[(size_t)row * ldo + col]);
                }
            }
        }
    }

#undef DO_PHASE
#undef STAGE
}

// ---------------------------------------------------------------------------
extern "C" void kernel_launch(void* const* d_in, const int* in_sizes, int n_in,
                              void* d_out, int out_size, void* d_ws, size_t ws_size,
                              hipStream_t stream) {
    const float* x  = (const float*)d_in[0];
    const float* Wq = (const float*)d_in[1];
    const float* Wk = (const float*)d_in[2];
    const float* Wv = (const float*)d_in[3];
    const float* bq = (const float*)d_in[4];
    const float* bk = (const float*)d_in[5];
    const float* bv = (const float*)d_in[6];
    const float* Aq = (const float*)d_in[7];
    const float* Bq = (const float*)d_in[8];
    const float* Ak = (const float*)d_in[9];
    const float* Bk = (const float*)d_in[10];
    const float* Av = (const float*)d_in[11];
    const float* Bv = (const float*)d_in[12];
    float* out = (float*)d_out;

    unsigned short* Xbf = (unsigned short*)d_ws;                   // 64 MB
    unsigned short* Wf  = Xbf + (size_t)Mdim * Kdim;               // 48 MB

    prep_kernel<<<WEFF_BLOCKS + CVT_BLOCKS, 256, 0, stream>>>(
        (const float4*)x, Xbf, Wq, Wk, Wv, Aq, Bq, Ak, Bk, Av, Bv, Wf);

    gemm_qkv_kernel<<<NWG, 512, 0, stream>>>(Xbf, Wf, bq, bk, bv, out);
}